// Round 9
// baseline (203.948 us; speedup 1.0000x reference)
//
#include <hip/hip_runtime.h>

#define KE_KCAL 332.0637f

constexpr int N_ATOMS = 6144;
constexpr int NREAL = 1200;             // sum_{bi<24} (96 - 4*bi)
constexpr int NPRED = 384;              // pred sub-blocks (16 atoms each)
constexpr int PAD = 32;                 // 32 words = 128 B line stride

// ws layout (bytes):
//   0     : ctr1[64*PAD] uint (8192)
//   8192  : ctr2 | 8196: pred_ctr | 8200: flag | 8204: cslot(float)
//   8448  : qpart[384] float
//   10240 : eblk[1200] float
//   16384 : xqp[6144] float4

// ---------------- init: zero the 8.4 KB control block -----------------------
__global__ __launch_bounds__(64) void init_kernel(unsigned int* __restrict__ c)
{
    for (int k = threadIdx.x; k < 2112; k += 64) c[k] = 0u;   // [0, 8448)
}

// ---------------- mega kernel: pred -> flag -> pair -> finalize -------------
__global__ __launch_bounds__(256, 8) void mega_kernel(
    const float* __restrict__ f, const int* __restrict__ z,
    const float* __restrict__ w, const float* __restrict__ ztab,
    const float* __restrict__ xyz, const float* __restrict__ qtot,
    float* __restrict__ qout, float* __restrict__ out0,
    unsigned int* __restrict__ ctr1, unsigned int* __restrict__ ctr2,
    unsigned int* __restrict__ pred_ctr, unsigned int* __restrict__ flag,
    float* __restrict__ cslot, float* __restrict__ qpart,
    float* __restrict__ eblk, float4* __restrict__ xqp)
{
    int t = threadIdx.x, b = blockIdx.x;
    int lane = t & 63, wid = t >> 6;
    __shared__ float lred[4];
    __shared__ float4 sj[64];
    __shared__ float sc;
    __shared__ int lflag, lfin;

    if (t == 0) lflag = 0;
    __syncthreads();

    // ---- phase 1: pred (blocks 0..383, 4 atoms/wave, proven body) ----
    if (b < NPRED) {
        int base = b * 16 + wid * 4;
        const float2* f2 = (const float2*)f;
        float2 wv = ((const float2*)w)[lane];
        float2 v0 = f2[(size_t)(base + 0) * 64 + lane];
        float2 v1 = f2[(size_t)(base + 1) * 64 + lane];
        float2 v2 = f2[(size_t)(base + 2) * 64 + lane];
        float2 v3 = f2[(size_t)(base + 3) * 64 + lane];
        float p0 = fmaf(v0.x, wv.x, v0.y * wv.y);
        float p1 = fmaf(v1.x, wv.x, v1.y * wv.y);
        float p2 = fmaf(v2.x, wv.x, v2.y * wv.y);
        float p3 = fmaf(v3.x, wv.x, v3.y * wv.y);
        #pragma unroll
        for (int off = 32; off > 0; off >>= 1) {
            p0 += __shfl_xor(p0, off, 64);
            p1 += __shfl_xor(p1, off, 64);
            p2 += __shfl_xor(p2, off, 64);
            p3 += __shfl_xor(p3, off, 64);
        }
        float ws_sum = 0.f;
        if (lane < 4) {
            int atom = base + lane;
            float pk = p0;
            pk = (lane == 1) ? p1 : pk;
            pk = (lane == 2) ? p2 : pk;
            pk = (lane == 3) ? p3 : pk;
            pk += ztab[z[atom]];
            xqp[atom] = make_float4(xyz[3*atom], xyz[3*atom+1], xyz[3*atom+2], pk);
            ws_sum = pk;
        }
        ws_sum += __shfl_xor(ws_sum, 1, 64);
        ws_sum += __shfl_xor(ws_sum, 2, 64);
        if (lane == 0) lred[wid] = ws_sum;
        __syncthreads();
        if (t == 0) {
            qpart[b] = lred[0] + lred[1] + lred[2] + lred[3];
            // release: orders qpart + xqp stores before the counter bump
            unsigned int old = __hip_atomic_fetch_add(pred_ctr, 1u,
                __ATOMIC_ACQ_REL, __HIP_MEMORY_SCOPE_AGENT);
            if (old == NPRED - 1u) lflag = 1;
        }
        __syncthreads();
        if (lflag) {                       // last pred block: publish corr
            float s2 = 0.f;
            for (int k = t; k < NPRED; k += 256)
                s2 += __hip_atomic_load(&qpart[k], __ATOMIC_RELAXED,
                                        __HIP_MEMORY_SCOPE_AGENT);
            #pragma unroll
            for (int off = 32; off > 0; off >>= 1)
                s2 += __shfl_xor(s2, off, 64);
            if (lane == 0) lred[wid] = s2;
            __syncthreads();
            if (t == 0) {
                float S = lred[0] + lred[1] + lred[2] + lred[3];
                float c = (qtot[0] - S) * (1.0f / (float)N_ATOMS);
                __hip_atomic_store(cslot, c, __ATOMIC_RELAXED,
                                   __HIP_MEMORY_SCOPE_AGENT);
                __hip_atomic_store(flag, 1u, __ATOMIC_RELEASE,
                                   __HIP_MEMORY_SCOPE_AGENT);
            }
        }
    }

    // ---- spin for corr (all 1200 blocks co-resident: 64 VGPR cap -> 8/CU) --
    if (t == 0) {
        while (__hip_atomic_load(flag, __ATOMIC_ACQUIRE,
                                 __HIP_MEMORY_SCOPE_AGENT) == 0u)
            __builtin_amdgcn_s_sleep(2);
        sc = __hip_atomic_load(cslot, __ATOMIC_RELAXED,
                               __HIP_MEMORY_SCOPE_AGENT);
    }
    __syncthreads();
    float corr = sc;

    // ---- phase 2: pair tile (R7 proven branchless body) ----
    int bi = 0, off = 0;
    while (b >= off + (96 - 4 * bi)) { off += 96 - 4 * bi; ++bi; }
    int bj = 4 * bi + (b - off);

    int gj0 = bj * 64;
    if (t < 64) {
        float4 a = xqp[gj0 + t];
        a.w += corr;
        sj[t] = a;
    }
    int gi = bi * 256 + t;
    float4 pi = xqp[gi];
    float qi = pi.w + corr;
    if (bj == 4 * bi) qout[gi] = qi;
    __syncthreads();

    int jthresh = gi - gj0;                   // pair valid iff jj > jthresh
    float acc = 0.f;
    #pragma unroll 4
    for (int jj = 0; jj < 64; ++jj) {
        float4 pj = sj[jj];
        float dx = pi.x - pj.x, dy = pi.y - pj.y, dz = pi.z - pj.z;
        float r2 = fmaf(dx, dx, fmaf(dy, dy, dz * dz));
        bool m = (jj > jthresh) && (r2 > 0.f);
        float r2s = m ? r2 : 1e8f;
        float qq  = m ? qi * pj.w : 0.f;
        float t2  = __builtin_amdgcn_rsqf(r2s);            // 1/r
        float u   = fmaf(r2s * t2, 0.2f, -0.5f);           // (r-2.5)/5
        u = fminf(fmaxf(u, 1e-3f), 0.999f);                // exact 0/1 sat
        float d   = (u + u - 1.f) * __builtin_amdgcn_rcpf(fmaf(-u, u, u));
        float fs  = __builtin_amdgcn_rcpf(1.f + __expf(d));
        float t1  = __builtin_amdgcn_rsqf(r2s + 1.f);      // 1/sqrt(r2+1)
        acc = fmaf(qq, fmaf(fs, t1 - t2, t2), acc);
    }

    #pragma unroll
    for (int o2 = 32; o2 > 0; o2 >>= 1)
        acc += __shfl_down(acc, o2, 64);
    __syncthreads();                          // lred reuse
    if (lane == 0) lred[wid] = acc;
    __syncthreads();
    if (t == 0) {
        eblk[b] = lred[0] + lred[1] + lred[2] + lred[3];
        int g = b & 63;
        unsigned int gcnt = (g < 48) ? 19u : 18u;   // 48*19 + 16*18 = 1200
        // release orders eblk store; acquire chains group -> global
        unsigned int o1 = __hip_atomic_fetch_add(&ctr1[g * PAD], 1u,
            __ATOMIC_ACQ_REL, __HIP_MEMORY_SCOPE_AGENT);
        int fin = 0;
        if (o1 == gcnt - 1u) {
            unsigned int o2c = __hip_atomic_fetch_add(ctr2, 1u,
                __ATOMIC_ACQ_REL, __HIP_MEMORY_SCOPE_AGENT);
            fin = (o2c == 63u);
        }
        lfin = fin;
    }
    __syncthreads();

    // ---- phase 3: last block reduces eblk -> energy ----
    if (lfin) {
        float e = 0.f;
        for (int k = t; k < NREAL; k += 256)
            e += __hip_atomic_load(&eblk[k], __ATOMIC_RELAXED,
                                   __HIP_MEMORY_SCOPE_AGENT);
        #pragma unroll
        for (int o2 = 32; o2 > 0; o2 >>= 1)
            e += __shfl_down(e, o2, 64);
        if (lane == 0) lred[wid] = e;
        __syncthreads();
        if (t == 0) out0[0] = KE_KCAL * (lred[0] + lred[1] + lred[2] + lred[3]);
    }
}

extern "C" void kernel_launch(void* const* d_in, const int* in_sizes, int n_in,
                              void* d_out, int out_size, void* d_ws, size_t ws_size,
                              hipStream_t stream) {
    const float* f    = (const float*)d_in[0];
    const int*   z    = (const int*)  d_in[1];
    const float* xyz  = (const float*)d_in[2];
    const float* qtot = (const float*)d_in[3];
    const float* w    = (const float*)d_in[4];
    const float* ztab = (const float*)d_in[5];
    float* out = (float*)d_out;            // out[0]=energy, out[1..N]=q

    char* wsb = (char*)d_ws;
    unsigned int* ctr1     = (unsigned int*)(wsb + 0);
    unsigned int* ctr2     = (unsigned int*)(wsb + 8192);
    unsigned int* pred_ctr = (unsigned int*)(wsb + 8196);
    unsigned int* flag     = (unsigned int*)(wsb + 8200);
    float*        cslot    = (float*)(wsb + 8204);
    float*        qpart    = (float*)(wsb + 8448);
    float*        eblk     = (float*)(wsb + 10240);
    float4*       xqp      = (float4*)(wsb + 16384);

    init_kernel<<<1, 64, 0, stream>>>((unsigned int*)wsb);
    mega_kernel<<<NREAL, 256, 0, stream>>>(f, z, w, ztab, xyz, qtot,
                                           out + 1, out, ctr1, ctr2,
                                           pred_ctr, flag, cslot, qpart,
                                           eblk, xqp);
}

// Round 10
// 105.457 us; speedup vs baseline: 1.9339x; 1.9339x over previous
//
#include <hip/hip_runtime.h>

#define KE_KCAL 332.0637f

constexpr int N_ATOMS = 6144;
constexpr int NREAL = 1200;             // sum_{bi<24} (96 - 4*bi)
constexpr int NPRED = 384;              // pred blocks (16 sorted slots each)
constexpr int PAD = 32;                 // 32 words = 128 B line stride
constexpr int NCELL = 512;              // 8x8x8 Morton cells, 7.5 A each

__device__ __forceinline__ unsigned spread3(unsigned v) {
    // 3-bit -> bits 0,3,6
    return (v & 1u) | ((v & 2u) << 2) | ((v & 4u) << 4);
}

__device__ __forceinline__ unsigned cell_of(float x, float y, float z) {
    unsigned cx = min(7u, (unsigned)(fmaxf(x, 0.f) * (8.0f / 60.0f)));
    unsigned cy = min(7u, (unsigned)(fmaxf(y, 0.f) * (8.0f / 60.0f)));
    unsigned cz = min(7u, (unsigned)(fmaxf(z, 0.f) * (8.0f / 60.0f)));
    return spread3(cx) | (spread3(cy) << 1) | (spread3(cz) << 2);
}

// ---------------- kernel S: Morton-cell counting sort (1 block) -------------
// Produces idx[s] = original atom at sorted slot s. Also zeroes epart/ctrs.
__global__ __launch_bounds__(512) void sort_kernel(
    const float* __restrict__ xyz, int* __restrict__ idx,
    float* __restrict__ epart, unsigned int* __restrict__ ctr1,
    unsigned int* __restrict__ ctr2)
{
    int t = threadIdx.x;
    int lane = t & 63, wv = t >> 6;     // 8 waves
    __shared__ unsigned cnt[NCELL];
    __shared__ unsigned basev[NCELL];
    __shared__ unsigned wsum[8];

    if (t < 64) { epart[t * PAD] = 0.f; ctr1[t * PAD] = 0u; }
    if (t == 64) *ctr2 = 0u;
    cnt[t] = 0u;                        // 512 threads, one cell each
    __syncthreads();

    for (int a = t; a < N_ATOMS; a += 512) {
        unsigned c = cell_of(xyz[3*a], xyz[3*a+1], xyz[3*a+2]);
        atomicAdd(&cnt[c], 1u);
    }
    __syncthreads();

    // exclusive scan over 512 bins: per-wave shfl scan + wave-offset pass
    unsigned v = cnt[t];
    unsigned x = v;
    #pragma unroll
    for (int off = 1; off < 64; off <<= 1) {
        unsigned y = __shfl_up(x, off, 64);
        if (lane >= off) x += y;
    }
    if (lane == 63) wsum[wv] = x;
    __syncthreads();
    if (t == 0) {
        unsigned acc = 0;
        #pragma unroll
        for (int k = 0; k < 8; ++k) { unsigned tmp = wsum[k]; wsum[k] = acc; acc += tmp; }
    }
    __syncthreads();
    basev[t] = x - v + wsum[wv];        // exclusive base per cell
    __syncthreads();

    for (int a = t; a < N_ATOMS; a += 512) {
        unsigned c = cell_of(xyz[3*a], xyz[3*a+1], xyz[3*a+2]);
        unsigned s = atomicAdd(&basev[c], 1u);
        idx[s] = a;
    }
}

// ---------------- kernel A: pred on sorted slots + per-block sums + pack ----
__global__ __launch_bounds__(256) void pred_kernel(
    const float* __restrict__ f, const int* __restrict__ z,
    const float* __restrict__ w, const float* __restrict__ ztab,
    const float* __restrict__ xyz, const int* __restrict__ idx,
    float* __restrict__ qpart, float4* __restrict__ xqp)
{
    int t = threadIdx.x, b = blockIdx.x;
    int lane = t & 63, wid = t >> 6;

    int sbase = b * 16 + wid * 4;       // 4 sorted slots per wave
    const int4 aq = ((const int4*)idx)[sbase >> 2];   // uniform -> s_load
    const float2* f2 = (const float2*)f;
    float2 wvv = ((const float2*)w)[lane];
    float2 v0 = f2[(size_t)aq.x * 64 + lane];
    float2 v1 = f2[(size_t)aq.y * 64 + lane];
    float2 v2 = f2[(size_t)aq.z * 64 + lane];
    float2 v3 = f2[(size_t)aq.w * 64 + lane];
    float p0 = fmaf(v0.x, wvv.x, v0.y * wvv.y);
    float p1 = fmaf(v1.x, wvv.x, v1.y * wvv.y);
    float p2 = fmaf(v2.x, wvv.x, v2.y * wvv.y);
    float p3 = fmaf(v3.x, wvv.x, v3.y * wvv.y);
    #pragma unroll
    for (int off = 32; off > 0; off >>= 1) {
        p0 += __shfl_xor(p0, off, 64);
        p1 += __shfl_xor(p1, off, 64);
        p2 += __shfl_xor(p2, off, 64);
        p3 += __shfl_xor(p3, off, 64);
    }
    float ws_sum = 0.f;
    if (lane < 4) {
        int a = (lane == 0) ? aq.x : (lane == 1) ? aq.y : (lane == 2) ? aq.z : aq.w;
        float pk = p0;
        pk = (lane == 1) ? p1 : pk;
        pk = (lane == 2) ? p2 : pk;
        pk = (lane == 3) ? p3 : pk;
        pk += ztab[z[a]];
        xqp[sbase + lane] = make_float4(xyz[3*a], xyz[3*a+1], xyz[3*a+2], pk);
        ws_sum = pk;
    }
    ws_sum += __shfl_xor(ws_sum, 1, 64);
    ws_sum += __shfl_xor(ws_sum, 2, 64);

    __shared__ float lred[4];
    if (lane == 0) lred[wid] = ws_sum;
    __syncthreads();
    if (t == 0) qpart[b] = lred[0] + lred[1] + lred[2] + lred[3];
}

// ---------------- kernel B: pairwise energy on sorted atoms -----------------
// 1200 triangular blocks x 256 threads in SORTED index space. Fast path
// (term = qq/r, exact for r >= 7.5) always; 5-transcendental switch
// correction only when __any lane of the wave has r2 < 56.25 — after the
// Morton sort this is ~4% of wave-iters. q scattered to original order.
__global__ __launch_bounds__(256) void pair_kernel(
    const float4* __restrict__ xqp, const float* __restrict__ qpart,
    const float* __restrict__ total_charge, const int* __restrict__ idx,
    float* __restrict__ qout, float* __restrict__ epart,
    unsigned int* __restrict__ ctr1, unsigned int* __restrict__ ctr2,
    float* __restrict__ out0)
{
    int t = threadIdx.x, b = blockIdx.x;
    int lane = t & 63, wid = t >> 6;
    __shared__ float lred[4];
    __shared__ float4 sj[64];

    // charge correction from the 384 per-block partials (uniform)
    float s = qpart[t];
    if (t < NPRED - 256) s += qpart[256 + t];
    #pragma unroll
    for (int off = 32; off > 0; off >>= 1)
        s += __shfl_xor(s, off, 64);
    if (lane == 0) lred[wid] = s;
    __syncthreads();
    float S = lred[0] + lred[1] + lred[2] + lred[3];
    float corr = (total_charge[0] - S) * (1.0f / (float)N_ATOMS);

    // decode triangular (bi, bj): bj in [4*bi, 96)
    int bi = 0, off = 0;
    while (b >= off + (96 - 4 * bi)) { off += 96 - 4 * bi; ++bi; }
    int bj = 4 * bi + (b - off);

    int gj0 = bj * 64;
    if (t < 64) {
        float4 a = xqp[gj0 + t];
        a.w += corr;
        sj[t] = a;
    }
    int gi = bi * 256 + t;              // sorted slot
    float4 pi = xqp[gi];
    float qi = pi.w + corr;
    if (bj == 4 * bi) qout[idx[gi]] = qi;   // scatter to original order
    __syncthreads();

    int jthresh = gi - gj0;             // pair valid iff jj > jthresh
    float acc = 0.f;
    #pragma unroll 4
    for (int jj = 0; jj < 64; ++jj) {
        float4 pj = sj[jj];
        float dx = pi.x - pj.x, dy = pi.y - pj.y, dz = pi.z - pj.z;
        float r2 = fmaf(dx, dx, fmaf(dy, dy, dz * dz));
        bool m = (jj > jthresh) && (r2 > 0.f);
        float r2s = m ? r2 : 1e8f;
        float qq  = m ? qi * pj.w : 0.f;
        float t2  = __builtin_amdgcn_rsqf(r2s);            // 1/r
        acc = fmaf(qq, t2, acc);                           // exact for r>=7.5
        if (__any(r2s < 56.25f)) {
            // switch correction: qq*fs*(t1-t2); fs==0 exactly for r>=7.5
            float u = fmaf(r2s * t2, 0.2f, -0.5f);         // (r-2.5)/5
            u = fminf(fmaxf(u, 1e-3f), 0.999f);
            float d  = (u + u - 1.f) * __builtin_amdgcn_rcpf(fmaf(-u, u, u));
            float fs = __builtin_amdgcn_rcpf(1.f + __expf(d));
            float t1 = __builtin_amdgcn_rsqf(r2s + 1.f);
            acc = fmaf(qq * fs, t1 - t2, acc);
        }
    }

    #pragma unroll
    for (int o2 = 32; o2 > 0; o2 >>= 1)
        acc += __shfl_down(acc, o2, 64);
    __syncthreads();                    // lred reuse
    if (lane == 0) lred[wid] = acc;
    __syncthreads();
    if (t == 0) {
        float be = lred[0] + lred[1] + lred[2] + lred[3];
        atomicAdd(&epart[(b & 63) * PAD], be);
    }

    // two-level completion + finalize (wave 0 only)
    if (t < 64) {
        bool last = false;
        if (t == 0) {
            int g = b & 63;
            unsigned int gcnt = (g < 48) ? 19u : 18u;   // 48*19 + 16*18 = 1200
            __threadfence();
            unsigned int o1 = atomicAdd(&ctr1[g * PAD], 1u);
            if (o1 == gcnt - 1u) {
                __threadfence();
                unsigned int o2c = atomicAdd(ctr2, 1u);
                last = (o2c == 63u);
            }
        }
        last = (bool)__shfl((int)last, 0, 64);
        if (last) {
            float e = atomicAdd(&epart[t * PAD], 0.0f);   // coherent read
            #pragma unroll
            for (int o2 = 32; o2 > 0; o2 >>= 1)
                e += __shfl_down(e, o2, 64);
            if (t == 0) out0[0] = KE_KCAL * e;
        }
    }
}

extern "C" void kernel_launch(void* const* d_in, const int* in_sizes, int n_in,
                              void* d_out, int out_size, void* d_ws, size_t ws_size,
                              hipStream_t stream) {
    const float* f    = (const float*)d_in[0];
    const int*   z    = (const int*)  d_in[1];
    const float* xyz  = (const float*)d_in[2];
    const float* qtot = (const float*)d_in[3];
    const float* w    = (const float*)d_in[4];
    const float* ztab = (const float*)d_in[5];
    float* out = (float*)d_out;            // out[0]=energy, out[1..N]=q

    // ws: [0,8192) epart padded | [8192,16384) ctr1 padded | [16384] ctr2
    //     [16896,+1536) qpart[384] | [18432,+24576) idx[6144]
    //     [49152,+98304) xqp[N] float4
    char* wsb = (char*)d_ws;
    float*        epart = (float*)(wsb + 0);
    unsigned int* ctr1  = (unsigned int*)(wsb + 8192);
    unsigned int* ctr2  = (unsigned int*)(wsb + 16384);
    float*        qpart = (float*)(wsb + 16896);
    int*          idx   = (int*)(wsb + 18432);
    float4*       xqp   = (float4*)(wsb + 49152);

    sort_kernel<<<1, 512, 0, stream>>>(xyz, idx, epart, ctr1, ctr2);
    pred_kernel<<<NPRED, 256, 0, stream>>>(f, z, w, ztab, xyz, idx,
                                           qpart, xqp);
    pair_kernel<<<NREAL, 256, 0, stream>>>(xqp, qpart, qtot, idx, out + 1,
                                           epart, ctr1, ctr2, out);
}